// Round 12
// baseline (61.672 us; speedup 1.0000x reference)
//
#include <hip/hip_runtime.h>
#include <hip/hip_bf16.h>

#define BDIM 256
#define NDIM 512
#define CDIM 1000
#define RDIM 64
#define BK 64            // x K-tile (prepass image format, proven)
#define BKW 32           // W K-chunk
#define NTW 16           // W iters
#define NCLS 4           // classes per block

typedef __attribute__((ext_vector_type(4))) float f32x4;
typedef __attribute__((ext_vector_type(8))) short bf16x8;
typedef __attribute__((ext_vector_type(4))) unsigned int u32x4;

__device__ __forceinline__ uint32_t pk2(float lo, float hi) {
    unsigned short l = __builtin_bit_cast(unsigned short, __float2bfloat16(lo));
    unsigned short h = __builtin_bit_cast(unsigned short, __float2bfloat16(hi));
    return ((uint32_t)h << 16) | (uint32_t)l;
}

__device__ __forceinline__ void gload16(const void* g, void* l) {
    __builtin_amdgcn_global_load_lds(
        (const __attribute__((address_space(1))) void*)g,
        (__attribute__((address_space(3))) void*)l, 16, 0, 0);
}

// ---------------------------------------------------------------------------
// Pre-pass (proven r2..r10, unchanged): x fp32 [256][512] -> bf16 swizzled
// BK=64 tile images. Tile t: byte P = row*128 + (uIn ^ ((row&7)<<4)).
// ---------------------------------------------------------------------------
__global__ __launch_bounds__(256)
void Mahalanobis_xconv_kernel(const float* __restrict__ x, uint4* __restrict__ xws)
{
    const int tid = blockIdx.x * 256 + threadIdx.x;   // 0..16383
    const int t   = tid >> 11;                        // tile 0..7
    const int rem = tid & 2047;
    const int row = rem >> 3;                         // 0..255
    const int sIn = (rem & 7) << 4;                   // swizzled inner byte
    const int uIn = sIn ^ ((row & 7) << 4);           // unswizzled inner byte
    const int col0 = t * BK + (uIn >> 1);
    const float4* src = reinterpret_cast<const float4*>(x + (size_t)row * NDIM + col0);
    const float4 a = src[0], b = src[1];
    uint4 pk = {pk2(a.x, a.y), pk2(a.z, a.w), pk2(b.x, b.y), pk2(b.z, b.w)};
    xws[tid] = pk;
}

// ---------------------------------------------------------------------------
// Main kernel: 4 classes/block, grid 250 (1 block/CU), 512 threads = 8 waves
// (mr = wv>>2 owns 128 b-rows, cl = wv&3 owns 1 class). Total traffic 197 MB.
// FULL double-buffer streaming: issue W(t+1) [+x tile on even t] at iter top,
// compute current from the other buffers, ONE __syncthreads per iter (its
// vmcnt(0) drain = prefetch completion). HBM pipe never idles.
// W LDS: [256 rows][128 B fp32], granule-XOR (row&7)<<4 applied on the
// pre-swizzled global source AND the reads (rule #21 both-sides).
// ---------------------------------------------------------------------------
__global__ __launch_bounds__(512, 2)
void Mahalanobis_72834055405642_kernel(const char* __restrict__ xws,
                                       const float* __restrict__ w,
                                       const float* __restrict__ bias,
                                       float* __restrict__ out)
{
    __shared__ alignas(16) char  lds_x[2][BDIM * BK * 2];     // 2 x 32 KB bf16
    __shared__ alignas(16) char  lds_w[2][256 * BKW * 4];     // 2 x 32 KB fp32
    __shared__ alignas(16) float bias_lds[NCLS * NDIM];       // 8 KB
    __shared__ float sb_lds[NCLS * RDIM];                     // 1 KB

    const int tid  = threadIdx.x;
    const int lane = tid & 63;
    const int wv   = tid >> 6;        // 0..7
    const int l15  = lane & 15;
    const int lhi  = lane >> 4;
    const int mr   = wv >> 2;         // 0..1: owns rows mr*128..+127
    const int cl   = wv & 3;          // 0..3: owns class c0+cl
    const int c0   = blockIdx.x * NCLS;

    const char* wbytes = reinterpret_cast<const char*>(w) + (size_t)c0 * (RDIM * NDIM * 4);

    // x staging: linear copy of the prepass swizzled image (32 KB, 4 rounds)
    auto issueX = [&](int tx, int buf) {
        #pragma unroll
        for (int q = 0; q < 4; ++q)
            gload16(xws + (size_t)tx * 32768 + q * 8192 + wv * 1024 + (size_t)lane * 16,
                    lds_x[buf] + q * 8192 + wv * 1024);
    };
    // W staging: LDS linear [256 rows][128 B], source granule-pre-swizzled
    auto issueW = [&](int t, int buf) {
        #pragma unroll
        for (int q = 0; q < 4; ++q) {
            const int row = q * 64 + wv * 8 + (lane >> 3);        // 0..255
            const int inn = ((lane & 7) * 16) ^ ((row & 7) << 4); // 16B granule XOR
            gload16(wbytes + (size_t)row * 2048 + t * 128 + inn,
                    lds_w[buf] + q * 8192 + wv * 1024);
        }
    };

    const int jrow = tid >> 1;            // Sb: tile row 0..255
    const int jh   = tid & 1;             // Sb: 16-float half of the 32-k chunk
    const int swj  = (jrow & 7) << 4;

    f32x4 acc[8][4];
    #pragma unroll
    for (int m = 0; m < 8; ++m)
        #pragma unroll
        for (int n = 0; n < 4; ++n)
            acc[m][n] = (f32x4){0.f, 0.f, 0.f, 0.f};

    float sbp = 0.f;

    // ---- prologue: bias -> LDS (2048 floats, 16 B/thread); stage tile 0
    {
        const f32x4 bv = *reinterpret_cast<const f32x4*>(bias + (size_t)c0 * NDIM + tid * 4);
        *reinterpret_cast<f32x4*>(bias_lds + tid * 4) = bv;
    }
    issueX(0, 0);
    issueW(0, 0);
    __syncthreads();   // drains prologue gloads + bias ds_writes

    #pragma unroll
    for (int t = 0; t < NTW; ++t) {
        const int wb  = t & 1;            // current W buffer
        const int xb  = (t >> 1) & 1;     // current x buffer
        const int ks  = t & 1;            // k-step within the BK=64 x tile

        // ---- issue-early: next W chunk, and next x tile on even iters
        if (t < NTW - 1) issueW(t + 1, wb ^ 1);
        if ((t & 1) == 0 && t < NTW - 2) issueX((t >> 1) + 1, xb ^ 1);

        // ---- Sb partial: row jrow, 16 floats at k = t*32 + jh*16
        {
            const char*  wp = lds_w[wb] + jrow * 128;
            const float* bl = bias_lds + (jrow >> 6) * NDIM + t * BKW + jh * 16;
            #pragma unroll
            for (int i = 0; i < 4; ++i) {
                const f32x4 wv4 = *reinterpret_cast<const f32x4*>(
                    wp + ((jh * 64 + i * 16) ^ swj));
                const f32x4 bv4 = *reinterpret_cast<const f32x4*>(bl + i * 4);
                sbp += wv4[0]*bv4[0] + wv4[1]*bv4[1] + wv4[2]*bv4[2] + wv4[3]*bv4[3];
            }
        }

        // ---- A-frags from the bf16 x image (proven addressing)
        bf16x8 af[8];
        #pragma unroll
        for (int m = 0; m < 8; ++m) {
            const int row = mr * 128 + m * 16 + l15;
            af[m] = *reinterpret_cast<const bf16x8*>(
                lds_x[xb] + row * 128 + ((ks * 64 + lhi * 16) ^ ((row & 7) << 4)));
        }

        // ---- B-frags JIT fp32->bf16 + MFMA (32 MFMA/wave/iter)
        #pragma unroll
        for (int n = 0; n < 4; ++n) {
            const int row = cl * RDIM + n * 16 + l15;       // 0..255
            const char* pp = lds_w[wb] + row * 128;
            const int sw = (row & 7) << 4;
            const f32x4 wlo = *reinterpret_cast<const f32x4*>(pp + ((lhi * 32) ^ sw));
            const f32x4 whi = *reinterpret_cast<const f32x4*>(pp + ((lhi * 32 + 16) ^ sw));
            u32x4 pk = {pk2(wlo[0], wlo[1]), pk2(wlo[2], wlo[3]),
                        pk2(whi[0], whi[1]), pk2(whi[2], whi[3])};
            const bf16x8 bw = __builtin_bit_cast(bf16x8, pk);
            #pragma unroll
            for (int m = 0; m < 8; ++m)
                acc[m][n] = __builtin_amdgcn_mfma_f32_16x16x32_bf16(
                    af[m], bw, acc[m][n], 0, 0, 0);
        }

        __syncthreads();   // drains t+1 prefetch; orders buffer reuse
    }

    // ---- Sb: pair-reduce halves (lane, lane^1), publish row sums
    sbp += __shfl_xor(sbp, 1);
    if (jh == 0) sb_lds[jrow] = sbp;
    __syncthreads();

    float sb[4];
    #pragma unroll
    for (int n = 0; n < 4; ++n) sb[n] = sb_lds[cl * RDIM + n * 16 + l15];

    // ---- epilogue: out[b, c0+cl] = sum_r (S - Sb)^2, butterfly over 16 lanes
    #pragma unroll
    for (int m = 0; m < 8; ++m) {
        #pragma unroll
        for (int rg = 0; rg < 4; ++rg) {
            float p = 0.f;
            #pragma unroll
            for (int n = 0; n < 4; ++n) {
                const float d = acc[m][n][rg] - sb[n];
                p += d * d;
            }
            #pragma unroll
            for (int s = 1; s < 16; s <<= 1)
                p += __shfl_xor(p, s);
            if (l15 == 0) {
                const int b = mr * 128 + m * 16 + lhi * 4 + rg;
                out[(size_t)b * CDIM + c0 + cl] = p;
            }
        }
    }
}

// ---------------------------------------------------------------------------
// Fallback (round-3 proven kernel) for ws_size < 256 KB
// ---------------------------------------------------------------------------
__global__ __launch_bounds__(256, 4)
void Mahalanobis_fallback_kernel(const float* __restrict__ x,
                                 const float* __restrict__ w,
                                 const float* __restrict__ bias,
                                 float* __restrict__ out)
{
    __shared__ alignas(16) char lds_x[BDIM * BK * 2];
    __shared__ alignas(16) char lds_w[RDIM * BK * 2];
    __shared__ float sb_lds[RDIM];

    const int tid  = threadIdx.x;
    const int lane = tid & 63;
    const int wv   = tid >> 6;
    const int l15  = lane & 15;
    const int lhi  = lane >> 4;
    const int c0   = blockIdx.x;

    const int jrow = tid >> 2;
    const int jq   = tid & 3;
    const float* wbase = w + (size_t)c0 * (RDIM * NDIM) + (size_t)jrow * NDIM + jq * 16;
    const float* bbase = bias + (size_t)c0 * NDIM + jq * 16;

    f32x4 acc[4][4];
    #pragma unroll
    for (int m = 0; m < 4; ++m)
        #pragma unroll
        for (int n = 0; n < 4; ++n)
            acc[m][n] = (f32x4){0.f, 0.f, 0.f, 0.f};

    float sbp = 0.f;
    const int swr = (l15 & 7) << 4;
    const int sww = (jrow & 7) << 4;
    const int xrow = tid >> 2;
    const int xq   = tid & 3;

    for (int t = 0; t < 8; ++t) {
        const float4* wsrc = reinterpret_cast<const float4*>(wbase + t * BK);
        const float4* bsrc = reinterpret_cast<const float4*>(bbase + t * BK);
        float4 w0 = wsrc[0], w1 = wsrc[1], w2 = wsrc[2], w3 = wsrc[3];
        float4 b0 = bsrc[0], b1 = bsrc[1], b2 = bsrc[2], b3 = bsrc[3];

        #pragma unroll
        for (int p = 0; p < 4; ++p) {
            const int r = p * 64 + xrow;
            const float4* s = reinterpret_cast<const float4*>(
                x + (size_t)r * NDIM + t * BK + xq * 16);
            float4 va = s[0], vb = s[1], vc = s[2], vd = s[3];
            uint4 pa = {pk2(va.x, va.y), pk2(va.z, va.w), pk2(vb.x, vb.y), pk2(vb.z, vb.w)};
            uint4 pb = {pk2(vc.x, vc.y), pk2(vc.z, vc.w), pk2(vd.x, vd.y), pk2(vd.z, vd.w)};
            const int sw = (r & 7) << 4;
            char* rowp = lds_x + r * 128;
            *reinterpret_cast<uint4*>(rowp + ((xq * 32) ^ sw))      = pa;
            *reinterpret_cast<uint4*>(rowp + ((xq * 32 + 16) ^ sw)) = pb;
        }

        sbp += w0.x*b0.x + w0.y*b0.y + w0.z*b0.z + w0.w*b0.w
             + w1.x*b1.x + w1.y*b1.y + w1.z*b1.z + w1.w*b1.w
             + w2.x*b2.x + w2.y*b2.y + w2.z*b2.z + w2.w*b2.w
             + w3.x*b3.x + w3.y*b3.y + w3.z*b3.z + w3.w*b3.w;
        {
            char* rowp = lds_w + jrow * 128;
            uint4 pa = {pk2(w0.x, w0.y), pk2(w0.z, w0.w), pk2(w1.x, w1.y), pk2(w1.z, w1.w)};
            uint4 pb = {pk2(w2.x, w2.y), pk2(w2.z, w2.w), pk2(w3.x, w3.y), pk2(w3.z, w3.w)};
            *reinterpret_cast<uint4*>(rowp + ((jq * 32) ^ sww))      = pa;
            *reinterpret_cast<uint4*>(rowp + ((jq * 32 + 16) ^ sww)) = pb;
        }

        __syncthreads();

        #pragma unroll
        for (int ks = 0; ks < 2; ++ks) {
            bf16x8 af[4];
            bf16x8 bfr[4];
            #pragma unroll
            for (int m = 0; m < 4; ++m) {
                const int row = wv * 64 + m * 16 + l15;
                af[m] = *reinterpret_cast<const bf16x8*>(
                    lds_x + row * 128 + ((ks * 64 + lhi * 16) ^ swr));
            }
            #pragma unroll
            for (int n = 0; n < 4; ++n) {
                const int row = n * 16 + l15;
                bfr[n] = *reinterpret_cast<const bf16x8*>(
                    lds_w + row * 128 + ((ks * 64 + lhi * 16) ^ swr));
            }
            #pragma unroll
            for (int m = 0; m < 4; ++m)
                #pragma unroll
                for (int n = 0; n < 4; ++n)
                    acc[m][n] = __builtin_amdgcn_mfma_f32_16x16x32_bf16(
                        af[m], bfr[n], acc[m][n], 0, 0, 0);
        }

        __syncthreads();
    }

    sbp += __shfl_xor(sbp, 1);
    sbp += __shfl_xor(sbp, 2);
    if (jq == 0) sb_lds[jrow] = sbp;
    __syncthreads();

    float sb[4];
    #pragma unroll
    for (int n = 0; n < 4; ++n) sb[n] = sb_lds[n * 16 + l15];

    #pragma unroll
    for (int m = 0; m < 4; ++m) {
        #pragma unroll
        for (int rg = 0; rg < 4; ++rg) {
            float p = 0.f;
            #pragma unroll
            for (int n = 0; n < 4; ++n) {
                const float d = acc[m][n][rg] - sb[n];
                p += d * d;
            }
            #pragma unroll
            for (int s = 1; s < 16; s <<= 1)
                p += __shfl_xor(p, s);
            if (l15 == 0) {
                const int b = wv * 64 + m * 16 + lhi * 4 + rg;
                out[(size_t)b * CDIM + c0] = p;
            }
        }
    }
}

extern "C" void kernel_launch(void* const* d_in, const int* in_sizes, int n_in,
                              void* d_out, int out_size, void* d_ws, size_t ws_size,
                              hipStream_t stream) {
    const float* x    = (const float*)d_in[0];
    const float* w    = (const float*)d_in[1];
    const float* bias = (const float*)d_in[2];
    float* out = (float*)d_out;

    if (ws_size >= (size_t)(BDIM * NDIM * 2)) {   // 256 KB bf16 x tile images
        hipLaunchKernelGGL(Mahalanobis_xconv_kernel, dim3(64), dim3(256), 0, stream,
                           x, (uint4*)d_ws);
        hipLaunchKernelGGL(Mahalanobis_72834055405642_kernel, dim3(CDIM / NCLS), dim3(512),
                           0, stream, (const char*)d_ws, w, bias, out);
    } else {
        hipLaunchKernelGGL(Mahalanobis_fallback_kernel, dim3(CDIM), dim3(256),
                           0, stream, x, w, bias, out);
    }
}

// Round 13
// 42.632 us; speedup vs baseline: 1.4466x; 1.4466x over previous
//
#include <hip/hip_runtime.h>
#include <hip/hip_bf16.h>

#define BDIM 256
#define NDIM 512
#define CDIM 1000
#define RDIM 64
#define BK 64
#define NT (NDIM / BK)       // 8 K-tiles
#define XIMG (BDIM * BK * NT * 2)   // 262144 B = one bf16 x image

typedef __attribute__((ext_vector_type(4))) float f32x4;
typedef __attribute__((ext_vector_type(8))) short bf16x8;
typedef __attribute__((ext_vector_type(4))) unsigned int u32x4;

__device__ __forceinline__ uint32_t pk2(float lo, float hi) {
    unsigned short l = __builtin_bit_cast(unsigned short, __float2bfloat16(lo));
    unsigned short h = __builtin_bit_cast(unsigned short, __float2bfloat16(hi));
    return ((uint32_t)h << 16) | (uint32_t)l;
}

__device__ __forceinline__ void gload16(const void* g, void* l) {
    __builtin_amdgcn_global_load_lds(
        (const __attribute__((address_space(1))) void*)g,
        (__attribute__((address_space(3))) void*)l, 16, 0, 0);
}

// ---------------------------------------------------------------------------
// Pre-pass (proven r2..r9) extended: writes `nrep` identical bf16 swizzled
// x images (replica r at byte offset r*XIMG). Content per image unchanged:
// tile t, byte P = row*128 + (uIn ^ ((row&7)<<4)).
// ---------------------------------------------------------------------------
__global__ __launch_bounds__(256)
void Mahalanobis_xconv_kernel(const float* __restrict__ x, uint4* __restrict__ xws)
{
    const int gtid = blockIdx.x * 256 + threadIdx.x;  // 0 .. 16384*nrep-1
    const int tid  = gtid & 16383;                    // index within one image
    const int t    = tid >> 11;                       // tile 0..7
    const int rem  = tid & 2047;
    const int row  = rem >> 3;                        // 0..255
    const int sIn  = (rem & 7) << 4;                  // swizzled inner byte
    const int uIn  = sIn ^ ((row & 7) << 4);          // unswizzled inner byte
    const int col0 = t * BK + (uIn >> 1);
    const float4* src = reinterpret_cast<const float4*>(x + (size_t)row * NDIM + col0);
    const float4 a = src[0], b = src[1];
    uint4 pk = {pk2(a.x, a.y), pk2(a.z, a.w), pk2(b.x, b.y), pk2(b.z, b.w)};
    xws[gtid] = pk;                                   // replica = gtid>>14
}

// ---------------------------------------------------------------------------
// Main kernel: EXACT r9 champion (42.3 us) + XCD-local x replica selection.
// 2 classes/block (grid 500, 2 blocks/CU), serial 2-barrier loop, all
// staging via global_load_lds: x from the bf16 swizzled image replica of
// THIS block's XCD (keeps x reads XCD-local-L2, off the W fabric path);
// W as fp32 with pre-swizzled source (rule #21). B-frags JIT fp32->bf16,
// Sb fused from the fp32 W LDS tile.
// ---------------------------------------------------------------------------
__global__ __launch_bounds__(256, 2)
void Mahalanobis_72834055405642_kernel(const char* __restrict__ xws,
                                       const float* __restrict__ w,
                                       const float* __restrict__ bias,
                                       float* __restrict__ out,
                                       int repmask)
{
    __shared__ alignas(16) char  lds_x[BDIM * BK * 2];      // 32 KB bf16, wave-sliced
    __shared__ alignas(16) char  lds_w[128 * BK * 4];       // 32 KB fp32 (128 rows x 256 B)
    __shared__ alignas(16) float bias_lds[2 * NDIM];        // 4 KB
    __shared__ float sb_lds[128];                           // 512 B

    const int tid  = threadIdx.x;
    const int lane = tid & 63;
    const int wv   = tid >> 6;
    const int l15  = lane & 15;
    const int lhi  = lane >> 4;
    const int c0   = blockIdx.x * 2;

    // XCD-local x replica (XCC_ID is wave-uniform scalar; measured m09)
    int xcd;
    asm volatile("s_getreg_b32 %0, hwreg(HW_REG_XCC_ID)" : "=s"(xcd));
    const char* xb = xws + (size_t)(xcd & repmask) * XIMG;

    const char* wbytes = reinterpret_cast<const char*>(w) + (size_t)c0 * (RDIM * NDIM * 4);
    const int   winner = (lane & 15) * 16;   // 16B chunk within a 256B W row

    // x staging (r7/r9-proven): wave-uniform LDS base, lane*16 implicit
    auto issueX = [&](int t) {
        #pragma unroll
        for (int q = 0; q < 8; ++q)
            gload16(xb + (size_t)t * 32768 + wv * 8192 + q * 1024 + (size_t)lane * 16,
                    lds_x + wv * 8192 + q * 1024);
    };
    // W staging: 128 class-major tile rows, LDS linear, source pre-swizzled
    auto issueW = [&](int t) {
        #pragma unroll
        for (int q = 0; q < 8; ++q) {
            const int row = wv * 32 + q * 4 + (lane >> 4);            // 0..127
            gload16(wbytes + (size_t)row * 2048 + t * 256 + (winner ^ ((row & 7) << 5)),
                    lds_w + wv * 8192 + q * 1024);
        }
    };

    const int swr   = (l15 & 7) << 4;     // x-image read swizzle (bf16)
    const int jrow2 = tid >> 1;           // Sb: tile row 0..127
    const int jh    = tid & 1;            // Sb: 32-float half
    const int swj   = (jrow2 & 7) << 5;

    f32x4 acc[4][8];
    #pragma unroll
    for (int m = 0; m < 4; ++m)
        #pragma unroll
        for (int n = 0; n < 8; ++n)
            acc[m][n] = (f32x4){0.f, 0.f, 0.f, 0.f};

    float sbp = 0.f;

    // ---- prologue: bias -> LDS (16 B/thread)
    {
        const f32x4 bv = *reinterpret_cast<const f32x4*>(bias + (size_t)c0 * NDIM + tid * 4);
        *reinterpret_cast<f32x4*>(bias_lds + tid * 4) = bv;
    }

    for (int t = 0; t < NT; ++t) {
        issueX(t);
        issueW(t);
        __syncthreads();   // drains gloads (+ bias ds_writes on t=0)

        // A-frags, both k-steps
        bf16x8 af[4][2];
        #pragma unroll
        for (int m = 0; m < 4; ++m) {
            const int row = wv * 64 + m * 16 + l15;
            #pragma unroll
            for (int ks = 0; ks < 2; ++ks)
                af[m][ks] = *reinterpret_cast<const bf16x8*>(
                    lds_x + row * 128 + ((ks * 64 + lhi * 16) ^ swr));
        }

        // Sb partial: this thread covers tile row jrow2, half jh (32 floats)
        {
            const char*  wp = lds_w + jrow2 * 256;
            const float* bl = bias_lds + (jrow2 >> 6) * NDIM + t * BK + jh * 32;
            #pragma unroll
            for (int i = 0; i < 8; ++i) {
                const f32x4 wv4 = *reinterpret_cast<const f32x4*>(
                    wp + ((jh * 128 + i * 16) ^ swj));
                const f32x4 bv4 = *reinterpret_cast<const f32x4*>(bl + i * 4);
                sbp += wv4[0]*bv4[0] + wv4[1]*bv4[1] + wv4[2]*bv4[2] + wv4[3]*bv4[3];
            }
        }

        // MFMA: B-frags JIT from fp32 W tile (transient regs only)
        #pragma unroll
        for (int ks = 0; ks < 2; ++ks) {
            #pragma unroll
            for (int n = 0; n < 8; ++n) {
                const int row = n * 16 + l15;
                const char* pp = lds_w + row * 256 +
                                 ((ks * 128 + lhi * 32) ^ ((row & 7) << 5));
                const f32x4 wlo = *reinterpret_cast<const f32x4*>(pp);
                const f32x4 whi = *reinterpret_cast<const f32x4*>(pp + 16);
                u32x4 pk = {pk2(wlo[0], wlo[1]), pk2(wlo[2], wlo[3]),
                            pk2(whi[0], whi[1]), pk2(whi[2], whi[3])};
                const bf16x8 bw = __builtin_bit_cast(bf16x8, pk);
                #pragma unroll
                for (int m = 0; m < 4; ++m)
                    acc[m][n] = __builtin_amdgcn_mfma_f32_16x16x32_bf16(
                        af[m][ks], bw, acc[m][n], 0, 0, 0);
            }
        }

        __syncthreads();   // all LDS reads done before next-iter overwrite
    }

    // ---- Sb: pair-reduce halves (tid, tid^1), publish row sums
    sbp += __shfl_xor(sbp, 1);
    if (jh == 0) sb_lds[jrow2] = sbp;
    __syncthreads();

    float sb[8];
    #pragma unroll
    for (int n = 0; n < 8; ++n) sb[n] = sb_lds[n * 16 + l15];

    // ---- epilogue (r1-proven): out[b, c0 + {0,1}] = sum_r (S - Sb)^2
    #pragma unroll
    for (int m = 0; m < 4; ++m) {
        #pragma unroll
        for (int rg = 0; rg < 4; ++rg) {
            float p0 = 0.f, p1 = 0.f;
            #pragma unroll
            for (int n = 0; n < 4; ++n) {
                const float d0 = acc[m][n][rg]     - sb[n];
                const float d1 = acc[m][n + 4][rg] - sb[n + 4];
                p0 += d0 * d0;
                p1 += d1 * d1;
            }
            #pragma unroll
            for (int s = 1; s < 16; s <<= 1) {
                p0 += __shfl_xor(p0, s);
                p1 += __shfl_xor(p1, s);
            }
            if (l15 == 0) {
                const int b = wv * 64 + m * 16 + lhi * 4 + rg;
                float2 o2 = {p0, p1};
                *reinterpret_cast<float2*>(out + (size_t)b * CDIM + c0) = o2;
            }
        }
    }
}

// ---------------------------------------------------------------------------
// Fallback (round-3 proven kernel) for ws_size < one x image
// ---------------------------------------------------------------------------
__global__ __launch_bounds__(256, 4)
void Mahalanobis_fallback_kernel(const float* __restrict__ x,
                                 const float* __restrict__ w,
                                 const float* __restrict__ bias,
                                 float* __restrict__ out)
{
    __shared__ alignas(16) char lds_x[BDIM * BK * 2];
    __shared__ alignas(16) char lds_w[RDIM * BK * 2];
    __shared__ float sb_lds[RDIM];

    const int tid  = threadIdx.x;
    const int lane = tid & 63;
    const int wv   = tid >> 6;
    const int l15  = lane & 15;
    const int lhi  = lane >> 4;
    const int c0   = blockIdx.x;

    const int jrow = tid >> 2;
    const int jq   = tid & 3;
    const float* wbase = w + (size_t)c0 * (RDIM * NDIM) + (size_t)jrow * NDIM + jq * 16;
    const float* bbase = bias + (size_t)c0 * NDIM + jq * 16;

    f32x4 acc[4][4];
    #pragma unroll
    for (int m = 0; m < 4; ++m)
        #pragma unroll
        for (int n = 0; n < 4; ++n)
            acc[m][n] = (f32x4){0.f, 0.f, 0.f, 0.f};

    float sbp = 0.f;
    const int swr = (l15 & 7) << 4;
    const int sww = (jrow & 7) << 4;
    const int xrow = tid >> 2;
    const int xq   = tid & 3;

    for (int t = 0; t < NT; ++t) {
        const float4* wsrc = reinterpret_cast<const float4*>(wbase + t * BK);
        const float4* bsrc = reinterpret_cast<const float4*>(bbase + t * BK);
        float4 w0 = wsrc[0], w1 = wsrc[1], w2 = wsrc[2], w3 = wsrc[3];
        float4 b0 = bsrc[0], b1 = bsrc[1], b2 = bsrc[2], b3 = bsrc[3];

        #pragma unroll
        for (int p = 0; p < 4; ++p) {
            const int r = p * 64 + xrow;
            const float4* s = reinterpret_cast<const float4*>(
                x + (size_t)r * NDIM + t * BK + xq * 16);
            float4 va = s[0], vb = s[1], vc = s[2], vd = s[3];
            uint4 pa = {pk2(va.x, va.y), pk2(va.z, va.w), pk2(vb.x, vb.y), pk2(vb.z, vb.w)};
            uint4 pb = {pk2(vc.x, vc.y), pk2(vc.z, vc.w), pk2(vd.x, vd.y), pk2(vd.z, vd.w)};
            const int sw = (r & 7) << 4;
            char* rowp = lds_x + r * 128;
            *reinterpret_cast<uint4*>(rowp + ((xq * 32) ^ sw))      = pa;
            *reinterpret_cast<uint4*>(rowp + ((xq * 32 + 16) ^ sw)) = pb;
        }

        sbp += w0.x*b0.x + w0.y*b0.y + w0.z*b0.z + w0.w*b0.w
             + w1.x*b1.x + w1.y*b1.y + w1.z*b1.z + w1.w*b1.w
             + w2.x*b2.x + w2.y*b2.y + w2.z*b2.z + w2.w*b2.w
             + w3.x*b3.x + w3.y*b3.y + w3.z*b3.z + w3.w*b3.w;
        {
            char* rowp = lds_w + jrow * 128;
            uint4 pa = {pk2(w0.x, w0.y), pk2(w0.z, w0.w), pk2(w1.x, w1.y), pk2(w1.z, w1.w)};
            uint4 pb = {pk2(w2.x, w2.y), pk2(w2.z, w2.w), pk2(w3.x, w3.y), pk2(w3.z, w3.w)};
            *reinterpret_cast<uint4*>(rowp + ((jq * 32) ^ sww))      = pa;
            *reinterpret_cast<uint4*>(rowp + ((jq * 32 + 16) ^ sww)) = pb;
        }

        __syncthreads();

        #pragma unroll
        for (int ks = 0; ks < 2; ++ks) {
            bf16x8 af[4];
            bf16x8 bfr[4];
            #pragma unroll
            for (int m = 0; m < 4; ++m) {
                const int row = wv * 64 + m * 16 + l15;
                af[m] = *reinterpret_cast<const bf16x8*>(
                    lds_x + row * 128 + ((ks * 64 + lhi * 16) ^ swr));
            }
            #pragma unroll
            for (int n = 0; n < 4; ++n) {
                const int row = n * 16 + l15;
                bfr[n] = *reinterpret_cast<const bf16x8*>(
                    lds_w + row * 128 + ((ks * 64 + lhi * 16) ^ swr));
            }
            #pragma unroll
            for (int m = 0; m < 4; ++m)
                #pragma unroll
                for (int n = 0; n < 4; ++n)
                    acc[m][n] = __builtin_amdgcn_mfma_f32_16x16x32_bf16(
                        af[m], bfr[n], acc[m][n], 0, 0, 0);
        }

        __syncthreads();
    }

    sbp += __shfl_xor(sbp, 1);
    sbp += __shfl_xor(sbp, 2);
    if (jq == 0) sb_lds[jrow] = sbp;
    __syncthreads();

    float sb[4];
    #pragma unroll
    for (int n = 0; n < 4; ++n) sb[n] = sb_lds[n * 16 + l15];

    #pragma unroll
    for (int m = 0; m < 4; ++m) {
        #pragma unroll
        for (int rg = 0; rg < 4; ++rg) {
            float p = 0.f;
            #pragma unroll
            for (int n = 0; n < 4; ++n) {
                const float d = acc[m][n][rg] - sb[n];
                p += d * d;
            }
            #pragma unroll
            for (int s = 1; s < 16; s <<= 1)
                p += __shfl_xor(p, s);
            if (l15 == 0) {
                const int b = wv * 64 + m * 16 + lhi * 4 + rg;
                out[(size_t)b * CDIM + c0] = p;
            }
        }
    }
}

extern "C" void kernel_launch(void* const* d_in, const int* in_sizes, int n_in,
                              void* d_out, int out_size, void* d_ws, size_t ws_size,
                              hipStream_t stream) {
    const float* x    = (const float*)d_in[0];
    const float* w    = (const float*)d_in[1];
    const float* bias = (const float*)d_in[2];
    float* out = (float*)d_out;

    if (ws_size >= (size_t)XIMG) {
        // 8 XCD-local replicas if workspace allows, else single image (r9 behavior)
        const int nrep    = (ws_size >= (size_t)(8 * XIMG)) ? 8 : 1;
        const int repmask = nrep - 1;
        hipLaunchKernelGGL(Mahalanobis_xconv_kernel, dim3(64 * nrep), dim3(256), 0, stream,
                           x, (uint4*)d_ws);
        hipLaunchKernelGGL(Mahalanobis_72834055405642_kernel, dim3(CDIM / 2), dim3(256),
                           0, stream, (const char*)d_ws, w, bias, out, repmask);
    } else {
        hipLaunchKernelGGL(Mahalanobis_fallback_kernel, dim3(CDIM), dim3(256),
                           0, stream, x, w, bias, out);
    }
}